// Round 1
// baseline (120.172 us; speedup 1.0000x reference)
//
#include <hip/hip_runtime.h>
#include <hip/hip_bf16.h>
#include <stdint.h>

// PositionalSAE on MI355X.
// Memory-bound: streams W_enc (134MB) + W_dec (134MB) f32 once each.
// bf16 MFMA (16x16x32) with on-the-fly f32->bf16 conversion of weights.

#define D_IN   2048
#define CHUNK  4096
#define NR     4
#define RS     32      // rows per range
#define LN_EPS 1e-5f

typedef __attribute__((ext_vector_type(8))) short bf16x8;   // 8 bf16 = 4 VGPRs (MFMA A/B frag)
typedef __attribute__((ext_vector_type(4))) float f32x4;    // MFMA C/D frag

// round-to-nearest-even f32 -> bf16
__device__ __forceinline__ unsigned short f2bf(float f) {
  unsigned int u = __float_as_uint(f);
  u += 0x7fffu + ((u >> 16) & 1u);
  return (unsigned short)(u >> 16);
}

// ---------------------------------------------------------------------------
// Kernel 1: prep. xfrag[r][mt][kt(64)][lane(64)][8] bf16 in MFMA A-frag order:
//   element = x[m = mt*16 + (lane&15)][k = kt*32 + (lane>>4)*8 + j]
// where x = acts + pos_emb[r] - b_dec. Also zeroes the 256-float LN stats.
// ---------------------------------------------------------------------------
__global__ __launch_bounds__(256) void prep_kernel(
    const float* __restrict__ acts, const float* __restrict__ pos,
    const float* __restrict__ bdec, unsigned short* __restrict__ xfrag,
    float* __restrict__ stats) {
  unsigned tid = blockIdx.x * 256u + threadIdx.x;
  if (blockIdx.x == 0) stats[threadIdx.x] = 0.0f;   // 256 floats: sums[128], sumsq[128]
  unsigned lane = tid & 63u, kt = (tid >> 6) & 63u, mt = (tid >> 12) & 1u, r = tid >> 13;
  unsigned m  = mt * 16 + (lane & 15u);
  unsigned k0 = kt * 32 + (lane >> 4) * 8;
  const float* ap = acts + (size_t)(r * RS + m) * D_IN + k0;
  const float* pp = pos  + (size_t)r * D_IN + k0;
  const float* bp = bdec + k0;
  bf16x8 v;
#pragma unroll
  for (int j = 0; j < 8; ++j) v[j] = (short)f2bf(ap[j] + pp[j] - bp[j]);
  *reinterpret_cast<bf16x8*>(xfrag + (size_t)tid * 8) = v;
}

// ---------------------------------------------------------------------------
// Kernel 2: encoder GEMM. grid = 4 ranges * 256 n-tiles(16). 8 waves split
// K=2048 (8 kt each), LDS-reduce, write pre (f32) + atomicAdd row sums/sumsq.
// ---------------------------------------------------------------------------
__global__ __launch_bounds__(512) void enc_kernel(
    const unsigned short* __restrict__ xfrag, const float* __restrict__ Wenc,
    const float* __restrict__ benc, float* __restrict__ pre,
    float* __restrict__ stats) {
  const unsigned r = blockIdx.x >> 8, nt = blockIdx.x & 255u;
  const unsigned n0 = nt * 16;
  const unsigned w = threadIdx.x >> 6, lane = threadIdx.x & 63u;
  const unsigned col = lane & 15u, g = lane >> 4;

  f32x4 acc0 = {0.f, 0.f, 0.f, 0.f}, acc1 = acc0;
  const unsigned short* xa0 = xfrag + (size_t)(r * 2 + 0) * 64 * 64 * 8;
  const unsigned short* xa1 = xfrag + (size_t)(r * 2 + 1) * 64 * 64 * 8;

  for (unsigned kt = w * 8; kt < w * 8 + 8; ++kt) {
    bf16x8 a0 = *reinterpret_cast<const bf16x8*>(xa0 + ((size_t)kt * 64 + lane) * 8);
    bf16x8 a1 = *reinterpret_cast<const bf16x8*>(xa1 + ((size_t)kt * 64 + lane) * 8);
    // B frag: lane holds W[k = kt*32 + g*8 + j][n0 + col], j=0..7
    const float* wp = Wenc + ((size_t)r * D_IN + kt * 32 + g * 8) * CHUNK + n0 + col;
    float bv[8];
#pragma unroll
    for (int j = 0; j < 8; ++j) bv[j] = wp[(size_t)j * CHUNK];
    bf16x8 bfrag;
#pragma unroll
    for (int j = 0; j < 8; ++j) bfrag[j] = (short)f2bf(bv[j]);
    acc0 = __builtin_amdgcn_mfma_f32_16x16x32_bf16(a0, bfrag, acc0, 0, 0, 0);
    acc1 = __builtin_amdgcn_mfma_f32_16x16x32_bf16(a1, bfrag, acc1, 0, 0, 0);
  }

  __shared__ float red[7][2][64][4];   // 14 KiB
  if (w > 0) {
#pragma unroll
    for (int i = 0; i < 4; ++i) { red[w-1][0][lane][i] = acc0[i]; red[w-1][1][lane][i] = acc1[i]; }
  }
  __syncthreads();
  if (w == 0) {
    for (int ww = 0; ww < 7; ++ww)
#pragma unroll
      for (int i = 0; i < 4; ++i) { acc0[i] += red[ww][0][lane][i]; acc1[i] += red[ww][1][lane][i]; }
    float bias = benc[(size_t)r * CHUNK + n0 + col];
#pragma unroll
    for (int mt = 0; mt < 2; ++mt) {
#pragma unroll
      for (int i = 0; i < 4; ++i) {
        float v = (mt ? acc1[i] : acc0[i]) + bias;   // C frag: col=lane&15, row=g*4+i
        unsigned row = mt * 16 + g * 4 + i;
        pre[(size_t)(r * RS + row) * CHUNK + n0 + col] = v;
        float s = v, q = v * v;
#pragma unroll
        for (int off = 1; off < 16; off <<= 1) {     // reduce over 16 cols (same row)
          s += __shfl_xor(s, off, 16);
          q += __shfl_xor(q, off, 16);
        }
        if (col == 0) {
          atomicAdd(&stats[r * 32 + row], s);
          atomicAdd(&stats[128 + r * 32 + row], q);
        }
      }
    }
  }
}

// ---------------------------------------------------------------------------
// Kernel 3: finish LayerNorm + ReLU, emit decoder A-frags (bf16).
// featfrag[r][mt][kt(128)][lane(64)][8]
// ---------------------------------------------------------------------------
__global__ __launch_bounds__(256) void lnpack_kernel(
    const float* __restrict__ pre, const float* __restrict__ stats,
    const float* __restrict__ gamma, const float* __restrict__ beta,
    unsigned short* __restrict__ featfrag) {
  unsigned tid = blockIdx.x * 256u + threadIdx.x;
  unsigned lane = tid & 63u, kt = (tid >> 6) & 127u, mt = (tid >> 13) & 1u, r = tid >> 14;
  unsigned m  = mt * 16 + (lane & 15u);
  unsigned s0 = kt * 32 + (lane >> 4) * 8;
  float mu  = stats[r * 32 + m] * (1.f / CHUNK);
  float var = stats[128 + r * 32 + m] * (1.f / CHUNK) - mu * mu;
  float rsd = rsqrtf(var + LN_EPS);
  const float* pp = pre   + (size_t)(r * RS + m) * CHUNK + s0;
  const float* gp = gamma + (size_t)r * CHUNK + s0;
  const float* bp = beta  + (size_t)r * CHUNK + s0;
  bf16x8 v;
#pragma unroll
  for (int j = 0; j < 8; ++j) {
    float x = (pp[j] - mu) * rsd * gp[j] + bp[j];
    v[j] = (short)f2bf(fmaxf(x, 0.f));
  }
  *reinterpret_cast<bf16x8*>(featfrag + (size_t)tid * 8) = v;
}

// ---------------------------------------------------------------------------
// Kernel 4: decoder GEMM. grid = 4 ranges * 128 d-tiles(16). 8 waves split
// K=4096 (16 kt each), LDS-reduce, + b_dec, store d_out (full overwrite).
// ---------------------------------------------------------------------------
__global__ __launch_bounds__(512) void dec_kernel(
    const unsigned short* __restrict__ featfrag, const float* __restrict__ Wdec,
    const float* __restrict__ bdec, float* __restrict__ out) {
  const unsigned r = blockIdx.x >> 7, dt = blockIdx.x & 127u;
  const unsigned d0 = dt * 16;
  const unsigned w = threadIdx.x >> 6, lane = threadIdx.x & 63u;
  const unsigned col = lane & 15u, g = lane >> 4;
  f32x4 acc0 = {0.f, 0.f, 0.f, 0.f}, acc1 = acc0;
  const unsigned short* fa0 = featfrag + (size_t)(r * 2 + 0) * 128 * 64 * 8;
  const unsigned short* fa1 = featfrag + (size_t)(r * 2 + 1) * 128 * 64 * 8;

  for (unsigned kt = w * 16; kt < w * 16 + 16; ++kt) {
    bf16x8 a0 = *reinterpret_cast<const bf16x8*>(fa0 + ((size_t)kt * 64 + lane) * 8);
    bf16x8 a1 = *reinterpret_cast<const bf16x8*>(fa1 + ((size_t)kt * 64 + lane) * 8);
    const float* wp = Wdec + ((size_t)r * CHUNK + kt * 32 + g * 8) * D_IN + d0 + col;
    float bv[8];
#pragma unroll
    for (int j = 0; j < 8; ++j) bv[j] = wp[(size_t)j * D_IN];
    bf16x8 bfrag;
#pragma unroll
    for (int j = 0; j < 8; ++j) bfrag[j] = (short)f2bf(bv[j]);
    acc0 = __builtin_amdgcn_mfma_f32_16x16x32_bf16(a0, bfrag, acc0, 0, 0, 0);
    acc1 = __builtin_amdgcn_mfma_f32_16x16x32_bf16(a1, bfrag, acc1, 0, 0, 0);
  }

  __shared__ float red[7][2][64][4];
  if (w > 0) {
#pragma unroll
    for (int i = 0; i < 4; ++i) { red[w-1][0][lane][i] = acc0[i]; red[w-1][1][lane][i] = acc1[i]; }
  }
  __syncthreads();
  if (w == 0) {
    for (int ww = 0; ww < 7; ++ww)
#pragma unroll
      for (int i = 0; i < 4; ++i) { acc0[i] += red[ww][0][lane][i]; acc1[i] += red[ww][1][lane][i]; }
    float bias = bdec[d0 + col];
#pragma unroll
    for (int mt = 0; mt < 2; ++mt)
#pragma unroll
      for (int i = 0; i < 4; ++i) {
        float v = (mt ? acc1[i] : acc0[i]) + bias;
        unsigned row = mt * 16 + g * 4 + i;
        out[(size_t)(r * RS + row) * D_IN + d0 + col] = v;
      }
  }
}

// ---------------------------------------------------------------------------
extern "C" void kernel_launch(void* const* d_in, const int* in_sizes, int n_in,
                              void* d_out, int out_size, void* d_ws, size_t ws_size,
                              hipStream_t stream) {
  const float* acts = (const float*)d_in[0];
  const float* Wenc = (const float*)d_in[1];
  const float* benc = (const float*)d_in[2];
  const float* bdec = (const float*)d_in[3];
  const float* pos  = (const float*)d_in[4];
  const float* lnw  = (const float*)d_in[5];
  const float* lnb  = (const float*)d_in[6];
  const float* Wdec = (const float*)d_in[7];
  float* out = (float*)d_out;

  char* ws = (char*)d_ws;
  float* stats            = (float*)ws;                                   // 1 KiB (sums[128], sumsq[128])
  unsigned short* xfrag   = (unsigned short*)(ws + 1024);                 // 512 KiB
  float* pre              = (float*)(ws + 1024 + 512 * 1024);             // 2 MiB
  unsigned short* featfrg = (unsigned short*)(ws + 1024 + 512 * 1024 + 2 * 1024 * 1024); // 1 MiB

  prep_kernel  <<<128, 256, 0, stream>>>(acts, pos, bdec, xfrag, stats);
  enc_kernel   <<<1024, 512, 0, stream>>>(xfrag, Wenc, benc, pre, stats);
  lnpack_kernel<<<256, 256, 0, stream>>>(pre, stats, lnw, lnb, featfrg);
  dec_kernel   <<<512, 512, 0, stream>>>(featfrg, Wdec, bdec, out);
}

// Round 2
// 84.488 us; speedup vs baseline: 1.4224x; 1.4224x over previous
//
#include <hip/hip_runtime.h>
#include <hip/hip_bf16.h>
#include <stdint.h>

// PositionalSAE on MI355X — round 2.
// Streaming GEMMs: W tiles -> LDS via global_load_lds (16B/lane), transposed
// fragment assembly from LDS (8x strided ds_read_b32 + cvt), bf16 MFMA.
// 2 blocks/CU so double-buffer drain bubbles overlap across blocks.

#define D_IN   2048
#define CHUNK  4096
#define NR     4
#define RS     32
#define LN_EPS 1e-5f

typedef __attribute__((ext_vector_type(8))) short bf16x8;
typedef __attribute__((ext_vector_type(4))) float f32x4;

#define AS1 __attribute__((address_space(1)))
#define AS3 __attribute__((address_space(3)))

__device__ __forceinline__ void gload_lds16(const float* g, float* l) {
  __builtin_amdgcn_global_load_lds((const AS1 unsigned int*)g,
                                   (AS3 unsigned int*)l, 16, 0, 0);
}

__device__ __forceinline__ unsigned short f2bf(float f) {
  unsigned int u = __float_as_uint(f);
  u += 0x7fffu + ((u >> 16) & 1u);
  return (unsigned short)(u >> 16);
}

// ---------------------------------------------------------------------------
// Kernel 1: prep. xfrag[r][mt][kt(64)][lane(64)][8] bf16, MFMA A-frag order:
//   element j = x[m = mt*16 + (lane&15)][k = kt*32 + (lane>>4)*8 + j]
// x = acts + pos_emb[r] - b_dec. Also zeroes the 256-float LN stats.
// ---------------------------------------------------------------------------
__global__ __launch_bounds__(256) void prep_kernel(
    const float* __restrict__ acts, const float* __restrict__ pos,
    const float* __restrict__ bdec, unsigned short* __restrict__ xfrag,
    float* __restrict__ stats) {
  unsigned tid = blockIdx.x * 256u + threadIdx.x;
  if (blockIdx.x == 0) stats[threadIdx.x] = 0.0f;
  unsigned lane = tid & 63u, kt = (tid >> 6) & 63u, mt = (tid >> 12) & 1u, r = tid >> 13;
  unsigned m  = mt * 16 + (lane & 15u);
  unsigned k0 = kt * 32 + (lane >> 4) * 8;
  const float* ap = acts + (size_t)(r * RS + m) * D_IN + k0;
  const float* pp = pos  + (size_t)r * D_IN + k0;
  const float* bp = bdec + k0;
  bf16x8 v;
#pragma unroll
  for (int j = 0; j < 8; ++j) v[j] = (short)f2bf(ap[j] + pp[j] - bp[j]);
  *reinterpret_cast<bf16x8*>(xfrag + (size_t)tid * 8) = v;
}

// ---------------------------------------------------------------------------
// Kernel 2: encoder. grid = 4r x 128nt (BN=32) = 512 blocks, 8 waves.
// Waves: nsub = w>>2 (two 16-col subtiles), kq = w&3 (K quarter of each step's
// 128-row tile). 16 K-steps, double-buffered LDS staging via global_load_lds.
// ---------------------------------------------------------------------------
__global__ __launch_bounds__(512) void enc_kernel(
    const unsigned short* __restrict__ xfrag, const float* __restrict__ Wenc,
    const float* __restrict__ benc, float* __restrict__ pre,
    float* __restrict__ stats) {
  const unsigned r = blockIdx.x >> 7, nt = blockIdx.x & 127u;
  const unsigned n0 = nt * 32;
  const unsigned w = threadIdx.x >> 6, lane = threadIdx.x & 63u;
  const unsigned nsub = w >> 2, kq = w & 3u;
  const unsigned col = lane & 15u, g = lane >> 4;

  __shared__ float tiles[2][128 * 32];          // 32 KiB
  __shared__ float red[3][2][2][64][4];         // 24 KiB

  const unsigned srow = lane >> 3;              // staging: row within wave-load
  const unsigned scol = (lane & 7u) * 4u;       // staging: float col
  const float* gbase = Wenc + (size_t)r * D_IN * CHUNK + n0 + scol;

  f32x4 acc0 = {0.f,0.f,0.f,0.f}, acc1 = acc0;
  const unsigned short* xa = xfrag + (size_t)r * 2 * 64 * 64 * 8;

  // prologue: stage step 0
#pragma unroll
  for (int l = 0; l < 2; ++l) {
    const float* gp = gbase + (size_t)(w * 16 + l * 8 + srow) * CHUNK;
    gload_lds16(gp, &tiles[0][(w * 2 + l) * 256]);
  }
  __syncthreads();

  unsigned cur = 0;
  for (unsigned step = 0; step < 16; ++step) {
    if (step + 1 < 16) {
      const unsigned kb = (step + 1) * 128 + w * 16;
#pragma unroll
      for (int l = 0; l < 2; ++l) {
        const float* gp = gbase + (size_t)(kb + l * 8 + srow) * CHUNK;
        gload_lds16(gp, &tiles[cur ^ 1][(w * 2 + l) * 256]);
      }
    }
    const unsigned kt_global = step * 4 + kq;
    bf16x8 a0 = *(const bf16x8*)(xa + ((size_t)kt_global * 64 + lane) * 8);
    bf16x8 a1 = *(const bf16x8*)(xa + ((size_t)(64 + kt_global) * 64 + lane) * 8);
    const float* tb = &tiles[cur][(kq * 32 + g * 8) * 32 + nsub * 16 + col];
    bf16x8 bfrag;
#pragma unroll
    for (int j = 0; j < 8; ++j) bfrag[j] = (short)f2bf(tb[j * 32]);
    acc0 = __builtin_amdgcn_mfma_f32_16x16x32_bf16(a0, bfrag, acc0, 0, 0, 0);
    acc1 = __builtin_amdgcn_mfma_f32_16x16x32_bf16(a1, bfrag, acc1, 0, 0, 0);
    __syncthreads();
    cur ^= 1;
  }

  // cross-wave reduce over kq
  if (kq != 0) {
#pragma unroll
    for (int i = 0; i < 4; ++i) {
      red[kq - 1][nsub][0][lane][i] = acc0[i];
      red[kq - 1][nsub][1][lane][i] = acc1[i];
    }
  }
  __syncthreads();
  if (kq == 0) {
    for (int q = 0; q < 3; ++q)
#pragma unroll
      for (int i = 0; i < 4; ++i) {
        acc0[i] += red[q][nsub][0][lane][i];
        acc1[i] += red[q][nsub][1][lane][i];
      }
    const unsigned nc = n0 + nsub * 16 + col;
    float bias = benc[(size_t)r * CHUNK + nc];
#pragma unroll
    for (int mt = 0; mt < 2; ++mt) {
#pragma unroll
      for (int i = 0; i < 4; ++i) {
        float v = (mt ? acc1[i] : acc0[i]) + bias;
        unsigned row = mt * 16 + g * 4 + i;
        pre[(size_t)(r * RS + row) * CHUNK + nc] = v;
        float s = v, q2 = v * v;
#pragma unroll
        for (int off = 1; off < 16; off <<= 1) {
          s  += __shfl_xor(s, off, 16);
          q2 += __shfl_xor(q2, off, 16);
        }
        if (col == 0) {
          atomicAdd(&stats[r * 32 + row], s);
          atomicAdd(&stats[128 + r * 32 + row], q2);
        }
      }
    }
  }
}

// ---------------------------------------------------------------------------
// Kernel 3: finish LayerNorm + ReLU -> decoder A-frags bf16.
// featfrag[r][mt][kt(128)][lane][8]
// ---------------------------------------------------------------------------
__global__ __launch_bounds__(256) void lnpack_kernel(
    const float* __restrict__ pre, const float* __restrict__ stats,
    const float* __restrict__ gamma, const float* __restrict__ beta,
    unsigned short* __restrict__ featfrag) {
  unsigned tid = blockIdx.x * 256u + threadIdx.x;
  unsigned lane = tid & 63u, kt = (tid >> 6) & 127u, mt = (tid >> 13) & 1u, r = tid >> 14;
  unsigned m  = mt * 16 + (lane & 15u);
  unsigned s0 = kt * 32 + (lane >> 4) * 8;
  float mu  = stats[r * 32 + m] * (1.f / CHUNK);
  float var = stats[128 + r * 32 + m] * (1.f / CHUNK) - mu * mu;
  float rsd = rsqrtf(var + LN_EPS);
  const float* pp = pre   + (size_t)(r * RS + m) * CHUNK + s0;
  const float* gp = gamma + (size_t)r * CHUNK + s0;
  const float* bp = beta  + (size_t)r * CHUNK + s0;
  bf16x8 v;
#pragma unroll
  for (int j = 0; j < 8; ++j) {
    float x = (pp[j] - mu) * rsd * gp[j] + bp[j];
    v[j] = (short)f2bf(fmaxf(x, 0.f));
  }
  *reinterpret_cast<bf16x8*>(featfrag + (size_t)tid * 8) = v;
}

// ---------------------------------------------------------------------------
// Kernel 4: decoder. grid = 4r x 2h (K-split) x 64nt (BN=32) = 512 blocks.
// Each block: K' = 2048 of the 4096 chunk dims, 16 K-steps of 128.
// Writes partial sums to part[h]; finish_kernel adds halves + b_dec.
// ---------------------------------------------------------------------------
__global__ __launch_bounds__(512) void dec_kernel(
    const unsigned short* __restrict__ featfrag, const float* __restrict__ Wdec,
    float* __restrict__ part) {
  const unsigned nt = blockIdx.x & 63u, h = (blockIdx.x >> 6) & 1u, r = blockIdx.x >> 7;
  const unsigned n0 = nt * 32;
  const unsigned w = threadIdx.x >> 6, lane = threadIdx.x & 63u;
  const unsigned nsub = w >> 2, kq = w & 3u;
  const unsigned col = lane & 15u, g = lane >> 4;

  __shared__ float tiles[2][128 * 32];
  __shared__ float red[3][2][2][64][4];

  const unsigned srow = lane >> 3;
  const unsigned scol = (lane & 7u) * 4u;
  const float* gbase = Wdec + ((size_t)r * CHUNK + h * 2048) * D_IN + n0 + scol;

  f32x4 acc0 = {0.f,0.f,0.f,0.f}, acc1 = acc0;
  const unsigned short* fa = featfrag + (size_t)r * 2 * 128 * 64 * 8;

#pragma unroll
  for (int l = 0; l < 2; ++l) {
    const float* gp = gbase + (size_t)(w * 16 + l * 8 + srow) * D_IN;
    gload_lds16(gp, &tiles[0][(w * 2 + l) * 256]);
  }
  __syncthreads();

  unsigned cur = 0;
  for (unsigned step = 0; step < 16; ++step) {
    if (step + 1 < 16) {
      const unsigned kb = (step + 1) * 128 + w * 16;
#pragma unroll
      for (int l = 0; l < 2; ++l) {
        const float* gp = gbase + (size_t)(kb + l * 8 + srow) * D_IN;
        gload_lds16(gp, &tiles[cur ^ 1][(w * 2 + l) * 256]);
      }
    }
    const unsigned kt_global = h * 64 + step * 4 + kq;
    bf16x8 a0 = *(const bf16x8*)(fa + ((size_t)kt_global * 64 + lane) * 8);
    bf16x8 a1 = *(const bf16x8*)(fa + ((size_t)(128 + kt_global) * 64 + lane) * 8);
    const float* tb = &tiles[cur][(kq * 32 + g * 8) * 32 + nsub * 16 + col];
    bf16x8 bfrag;
#pragma unroll
    for (int j = 0; j < 8; ++j) bfrag[j] = (short)f2bf(tb[j * 32]);
    acc0 = __builtin_amdgcn_mfma_f32_16x16x32_bf16(a0, bfrag, acc0, 0, 0, 0);
    acc1 = __builtin_amdgcn_mfma_f32_16x16x32_bf16(a1, bfrag, acc1, 0, 0, 0);
    __syncthreads();
    cur ^= 1;
  }

  if (kq != 0) {
#pragma unroll
    for (int i = 0; i < 4; ++i) {
      red[kq - 1][nsub][0][lane][i] = acc0[i];
      red[kq - 1][nsub][1][lane][i] = acc1[i];
    }
  }
  __syncthreads();
  if (kq == 0) {
    for (int q = 0; q < 3; ++q)
#pragma unroll
      for (int i = 0; i < 4; ++i) {
        acc0[i] += red[q][nsub][0][lane][i];
        acc1[i] += red[q][nsub][1][lane][i];
      }
    const unsigned nc = n0 + nsub * 16 + col;
    float* pout = part + (size_t)h * 128 * D_IN;
#pragma unroll
    for (int mt = 0; mt < 2; ++mt)
#pragma unroll
      for (int i = 0; i < 4; ++i) {
        unsigned row = mt * 16 + g * 4 + i;
        pout[(size_t)(r * RS + row) * D_IN + nc] = (mt ? acc1[i] : acc0[i]);
      }
  }
}

// ---------------------------------------------------------------------------
// Kernel 5: out = part0 + part1 + b_dec (one float4 per thread).
// ---------------------------------------------------------------------------
__global__ __launch_bounds__(256) void finish_kernel(
    const float* __restrict__ part, const float* __restrict__ bdec,
    float* __restrict__ out) {
  unsigned i = blockIdx.x * 256u + threadIdx.x;           // float4 index
  f32x4 a = ((const f32x4*)part)[i];
  f32x4 b = ((const f32x4*)(part + 128 * D_IN))[i];
  f32x4 c = ((const f32x4*)bdec)[i & 511u];
  f32x4 o;
#pragma unroll
  for (int j = 0; j < 4; ++j) o[j] = a[j] + b[j] + c[j];
  ((f32x4*)out)[i] = o;
}

// ---------------------------------------------------------------------------
extern "C" void kernel_launch(void* const* d_in, const int* in_sizes, int n_in,
                              void* d_out, int out_size, void* d_ws, size_t ws_size,
                              hipStream_t stream) {
  const float* acts = (const float*)d_in[0];
  const float* Wenc = (const float*)d_in[1];
  const float* benc = (const float*)d_in[2];
  const float* bdec = (const float*)d_in[3];
  const float* pos  = (const float*)d_in[4];
  const float* lnw  = (const float*)d_in[5];
  const float* lnb  = (const float*)d_in[6];
  const float* Wdec = (const float*)d_in[7];
  float* out = (float*)d_out;

  char* ws = (char*)d_ws;
  float* stats            = (float*)ws;                                   // 1 KiB
  unsigned short* xfrag   = (unsigned short*)(ws + 1024);                 // 512 KiB
  float* pre              = (float*)(ws + 1024 + 512 * 1024);             // 2 MiB
  unsigned short* featfrg = (unsigned short*)(ws + 1024 + 512 * 1024 + 2 * 1024 * 1024); // 1 MiB
  float* part             = (float*)(ws + 1024 + 512 * 1024 + 3 * 1024 * 1024);          // 2 MiB

  prep_kernel  <<<128, 256, 0, stream>>>(acts, pos, bdec, xfrag, stats);
  enc_kernel   <<<512, 512, 0, stream>>>(xfrag, Wenc, benc, pre, stats);
  lnpack_kernel<<<256, 256, 0, stream>>>(pre, stats, lnw, lnb, featfrg);
  dec_kernel   <<<512, 512, 0, stream>>>(featfrg, Wdec, part);
  finish_kernel<<<256, 256, 0, stream>>>(part, bdec, out);
}